// Round 1
// baseline (53.417 us; speedup 1.0000x reference)
//
#include <hip/hip_runtime.h>

// out[j] = sum(x) for all j.
// Stage 1: per-block partial sums (float4 vectorized, grid-stride).
// Stage 2: single-block reduce of partials -> total scalar in ws.
// Stage 3: broadcast fill of out with total (float4 stores).

#define NBLK 2048
#define NTHR 256

__global__ __launch_bounds__(NTHR) void reduce_partial_kernel(
    const float4* __restrict__ x4, const float* __restrict__ x,
    float* __restrict__ partials, int n4, int n)
{
    int tid    = blockIdx.x * blockDim.x + threadIdx.x;
    int stride = gridDim.x * blockDim.x;

    float s = 0.0f;
    for (int i = tid; i < n4; i += stride) {
        float4 v = x4[i];
        s += (v.x + v.y) + (v.z + v.w);
    }
    // scalar tail (n not divisible by 4): handled by first few threads
    int tail_start = n4 * 4;
    int tail_n = n - tail_start;
    if (tid < tail_n) s += x[tail_start + tid];

    // wave-64 butterfly reduce
    #pragma unroll
    for (int off = 32; off > 0; off >>= 1)
        s += __shfl_down(s, off, 64);

    __shared__ float smem[NTHR / 64];
    int lane = threadIdx.x & 63;
    int wid  = threadIdx.x >> 6;
    if (lane == 0) smem[wid] = s;
    __syncthreads();
    if (threadIdx.x == 0) {
        float t = 0.0f;
        #pragma unroll
        for (int w = 0; w < NTHR / 64; ++w) t += smem[w];
        partials[blockIdx.x] = t;
    }
}

__global__ __launch_bounds__(NTHR) void reduce_final_kernel(
    const float* __restrict__ partials, float* __restrict__ total, int n)
{
    float s = 0.0f;
    for (int i = threadIdx.x; i < n; i += blockDim.x) s += partials[i];

    #pragma unroll
    for (int off = 32; off > 0; off >>= 1)
        s += __shfl_down(s, off, 64);

    __shared__ float smem[NTHR / 64];
    int lane = threadIdx.x & 63;
    int wid  = threadIdx.x >> 6;
    if (lane == 0) smem[wid] = s;
    __syncthreads();
    if (threadIdx.x == 0) {
        float t = 0.0f;
        #pragma unroll
        for (int w = 0; w < NTHR / 64; ++w) t += smem[w];
        *total = t;
    }
}

__global__ __launch_bounds__(NTHR) void fill_total_kernel(
    float4* __restrict__ out4, float* __restrict__ out,
    const float* __restrict__ total, int n4, int n)
{
    float t = *total;
    float4 v = make_float4(t, t, t, t);

    int tid    = blockIdx.x * blockDim.x + threadIdx.x;
    int stride = gridDim.x * blockDim.x;
    for (int i = tid; i < n4; i += stride) out4[i] = v;

    int tail_start = n4 * 4;
    int tail_n = n - tail_start;
    if (tid < tail_n) out[tail_start + tid] = t;
}

extern "C" void kernel_launch(void* const* d_in, const int* in_sizes, int n_in,
                              void* d_out, int out_size, void* d_ws, size_t ws_size,
                              hipStream_t stream)
{
    const float*  x   = (const float*)d_in[0];
    const float4* x4  = (const float4*)d_in[0];
    float*        out = (float*)d_out;
    float4*       out4 = (float4*)d_out;

    int n  = in_sizes[0];
    int n4 = n / 4;

    float* partials = (float*)d_ws;          // NBLK floats
    float* total    = partials + NBLK;       // 1 float

    reduce_partial_kernel<<<NBLK, NTHR, 0, stream>>>(x4, x, partials, n4, n);
    reduce_final_kernel<<<1, NTHR, 0, stream>>>(partials, total, NBLK);
    fill_total_kernel<<<NBLK, NTHR, 0, stream>>>(out4, out, total, n4, out_size);
}